// Round 3
// baseline (612.937 us; speedup 1.0000x reference)
//
#include <hip/hip_runtime.h>
#include <math.h>

#define B_N 2048
#define D_FT 784
#define K_N 50
#define L_N 6
#define LOG2PI_F 1.8378770664093453f

// ---- output layout (floats), concatenated in reference return order ----
#define OUT_PW 0
#define OUT_M  (B_N)                              // 2048
#define OUT_A  (OUT_M + B_N*D_FT)                 // 1607680
#define OUT_D  (OUT_A + B_N*D_FT*6)               // 11241472

// ---- workspace layout (float offsets) ----
#define WS_SCORES 0                                // [K][B]     102400
#define WS_PQ     (WS_SCORES + K_N*B_N)            // [K][27][B] 2764800
#define WS_C      (WS_PQ + K_N*27*B_N)             // [B] int    2048
#define WS_MZLZ   (WS_C + B_N)                     // [B][28]    57344
#define WS_XT     (WS_MZLZ + B_N*28)               // [D/4][B] float4 = D*B floats
#define WS_JBT    (WS_XT + D_FT*B_N)               // [25][B]    51200

#define IDX(i,j) ((i)*((i)+1)/2 + (j))   // packed lower, i>=j

// ---------- 6x6 packed-lower Cholesky ----------
__device__ __forceinline__ void chol6(const float* P, float* L, float* rd, float* sumlog) {
    float sl = 0.f;
    #pragma unroll
    for (int j = 0; j < 6; ++j) {
        float s = P[IDX(j,j)];
        #pragma unroll
        for (int m = 0; m < j; ++m) s -= L[IDX(j,m)] * L[IDX(j,m)];
        float d = sqrtf(s);
        L[IDX(j,j)] = d;
        float r = 1.0f / d;
        rd[j] = r;
        sl += logf(d);
        #pragma unroll
        for (int i = j + 1; i < 6; ++i) {
            float t = P[IDX(i,j)];
            #pragma unroll
            for (int m = 0; m < j; ++m) t -= L[IDX(i,m)] * L[IDX(j,m)];
            L[IDX(i,j)] = t * r;
        }
    }
    *sumlog = sl;
}

// ---------- K0: transpose X [B][D] -> Xt4 [D/4][B] (float4 per cell) ----------
__global__ __launch_bounds__(1024) void k_transpose4(const float* __restrict__ X,
                                                     float4* __restrict__ Xt4) {
    __shared__ float4 tile[32][33];
    int tx = threadIdx.x, ty = threadIdx.y;
    int d4b = blockIdx.x * 32;
    int bb  = blockIdx.y * 32;
    int d4 = d4b + tx;
    if (d4 < D_FT / 4)
        tile[ty][tx] = *(const float4*)&X[(size_t)(bb + ty) * D_FT + d4 * 4];
    __syncthreads();
    int d4o = d4b + ty;
    if (d4o < D_FT / 4)
        Xt4[(size_t)d4o * B_N + (bb + tx)] = tile[tx][ty];
}

// ---------- K0b: pack J bits -> JbT[w][b], w in [0,25) ----------
__global__ void k_packbits(const int* __restrict__ J, unsigned* __restrict__ JbT) {
    int t = blockIdx.x * blockDim.x + threadIdx.x;   // 2048*32 threads
    int b = t >> 5;
    int w = t & 31;
    if (w >= 25) return;
    int d0 = w * 32;
    int n = D_FT - d0; if (n > 32) n = 32;
    unsigned u = 0;
    for (int j = 0; j < n; ++j)
        u |= (J[(size_t)b * D_FT + d0 + j] != 0 ? 1u : 0u) << j;
    JbT[(size_t)w * B_N + b] = u;
}

// ---------- K1: per-(sample,k) accumulation + loglik ----------
// 512 threads = 128 samples x 4 d-quarters. quarter h covers words h*6..h*6+5
// (h==3: words 18..24 incl. 16-bit tail word 24).
#define ACC_BODY(dd, xval) do { \
    const int d_ = wbase + (dd); \
    const float* r_ = &smem[d_ * 12]; \
    float mf = (float)((mw >> (dd)) & 1u); \
    float a0=r_[0], a1=r_[1], a2=r_[2], a3=r_[3], a4=r_[4], a5=r_[5]; \
    float giD = mf * r_[6]; \
    float xm = (xval) - r_[8]; \
    float md = mf * xm; \
    jld += mf * r_[7]; \
    float u0=giD*a0, u1=giD*a1, u2=giD*a2, u3=giD*a3, u4=giD*a4, u5=giD*a5; \
    Pm[0]  += u0*a0; \
    Pm[1]  += u1*a0; Pm[2]  += u1*a1; \
    Pm[3]  += u2*a0; Pm[4]  += u2*a1; Pm[5]  += u2*a2; \
    Pm[6]  += u3*a0; Pm[7]  += u3*a1; Pm[8]  += u3*a2; Pm[9]  += u3*a3; \
    Pm[10] += u4*a0; Pm[11] += u4*a1; Pm[12] += u4*a2; Pm[13] += u4*a3; Pm[14] += u4*a4; \
    Pm[15] += u5*a0; Pm[16] += u5*a1; Pm[17] += u5*a2; Pm[18] += u5*a3; Pm[19] += u5*a4; Pm[20] += u5*a5; \
    qv[0] += md*u0; qv[1] += md*u1; qv[2] += md*u2; \
    qv[3] += md*u3; qv[4] += md*u4; qv[5] += md*u5; \
    float tq = md * md; \
    quad += tq * giD; \
} while (0)

__global__ __launch_bounds__(512, 8) void k_accum(
        const float4* __restrict__ Xt4, const unsigned* __restrict__ JbT,
        const float* __restrict__ A, const float* __restrict__ MU,
        const float* __restrict__ logD, const float* __restrict__ PI,
        float* __restrict__ scores, float* __restrict__ Pq) {
    __shared__ float smem[D_FT * 12];   // 37632 B; aliased as reduction buffer later
    const int k   = blockIdx.x >> 4;
    const int tid = threadIdx.x;
    const int s   = tid & 127;
    const int h   = tid >> 7;           // d-quarter 0..3
    const int b   = (blockIdx.x & 15) * 128 + s;

    for (int i = tid; i < D_FT; i += 512) {
        const float* ar = A + ((size_t)k * D_FT + i) * 6;
        float* r = &smem[i * 12];
        r[0]=ar[0]; r[1]=ar[1]; r[2]=ar[2]; r[3]=ar[3]; r[4]=ar[4]; r[5]=ar[5];
        float ld = logD[(size_t)k * D_FT + i];
        r[6] = expf(-ld);
        r[7] = ld;
        r[8] = MU[(size_t)k * D_FT + i];
    }
    __syncthreads();

    float Pm[21], qv[6];
    #pragma unroll
    for (int t = 0; t < 21; ++t) Pm[t] = 0.f;
    #pragma unroll
    for (int t = 0; t < 6; ++t) qv[t] = 0.f;
    float quad = 0.f, jld = 0.f;
    int nob = 0;

    const int w0 = h * 6;
    const int w1 = w0 + 6;              // h==3: words 18..23 full, word 24 tail below
    for (int w = w0; w < w1; ++w) {
        const unsigned mw = JbT[(size_t)w * B_N + b];
        nob += __popc(mw);
        const int wbase = w * 32;
        const float4* xp = Xt4 + (size_t)(w * 8) * B_N + b;
        #pragma unroll 4
        for (int g = 0; g < 8; ++g) {
            float4 xv = xp[(size_t)g * B_N];
            ACC_BODY(g * 4 + 0, xv.x);
            ACC_BODY(g * 4 + 1, xv.y);
            ACC_BODY(g * 4 + 2, xv.z);
            ACC_BODY(g * 4 + 3, xv.w);
        }
    }
    if (h == 3) {  // tail word 24: bits 0..15 valid (packed zeros above)
        const unsigned mw = JbT[(size_t)24 * B_N + b];
        nob += __popc(mw);
        const int wbase = 768;
        const float4* xp = Xt4 + (size_t)(24 * 8) * B_N + b;
        #pragma unroll
        for (int g = 0; g < 4; ++g) {
            float4 xv = xp[(size_t)g * B_N];
            ACC_BODY(g * 4 + 0, xv.x);
            ACC_BODY(g * 4 + 1, xv.y);
            ACC_BODY(g * 4 + 2, xv.z);
            ACC_BODY(g * 4 + 3, xv.w);
        }
    }

    // merge the 4 d-quarters through LDS (staging buffer is dead now).
    // round A: h==1 -> slab 0, h==3 -> slab 1; h==0/h==2 accumulate.
    // round B: h==2 -> slab 0; h==0 accumulates + epilogue.
    __syncthreads();
    float* red = smem;
    if (h & 1) {
        float* o = &red[(size_t)(h >> 1) * (128 * 33) + s * 33];
        #pragma unroll
        for (int t = 0; t < 21; ++t) o[t] = Pm[t];
        #pragma unroll
        for (int t = 0; t < 6; ++t) o[21 + t] = qv[t];
        o[27] = quad; o[28] = jld; o[29] = (float)nob;
    }
    __syncthreads();
    if (!(h & 1)) {
        const float* o = &red[(size_t)(h >> 1) * (128 * 33) + s * 33];
        #pragma unroll
        for (int t = 0; t < 21; ++t) Pm[t] += o[t];
        #pragma unroll
        for (int t = 0; t < 6; ++t) qv[t] += o[21 + t];
        quad += o[27]; jld += o[28]; nob += (int)o[29];
    }
    __syncthreads();
    if (h == 2) {
        float* o = &red[s * 33];
        #pragma unroll
        for (int t = 0; t < 21; ++t) o[t] = Pm[t];
        #pragma unroll
        for (int t = 0; t < 6; ++t) o[21 + t] = qv[t];
        o[27] = quad; o[28] = jld; o[29] = (float)nob;
    }
    __syncthreads();
    if (h == 0) {
        const float* o = &red[s * 33];
        #pragma unroll
        for (int t = 0; t < 21; ++t) Pm[t] += o[t];
        #pragma unroll
        for (int t = 0; t < 6; ++t) qv[t] += o[21 + t];
        quad += o[27]; jld += o[28];
        float nobs = (float)nob + o[29];

        // P = I + sum
        Pm[0] += 1.f; Pm[2] += 1.f; Pm[5] += 1.f; Pm[9] += 1.f; Pm[14] += 1.f; Pm[20] += 1.f;

        float Lm[21], rd[6], sumlog;
        chol6(Pm, Lm, rd, &sumlog);
        float y[6];
        #pragma unroll
        for (int j = 0; j < 6; ++j) {
            float sv = qv[j];
            #pragma unroll
            for (int m = 0; m < j; ++m) sv -= Lm[IDX(j,m)] * y[m];
            y[j] = sv * rd[j];
        }
        float yy = 0.f;
        #pragma unroll
        for (int j = 0; j < 6; ++j) yy += y[j] * y[j];
        float logdet = 2.f * sumlog + jld;
        float ll = -0.5f * ((quad - yy) + logdet + nobs * LOG2PI_F);
        float score = ll + PI[k];

        scores[(size_t)k * B_N + b] = score;
        float* pq = Pq + (size_t)k * 27 * B_N + b;
        #pragma unroll
        for (int t = 0; t < 21; ++t) pq[(size_t)t * B_N] = Pm[t];
        #pragma unroll
        for (int t = 0; t < 6; ++t) pq[(size_t)(21 + t) * B_N] = qv[t];
    }
}

// ---------- KC: argmax + latent solve per sample ----------
__global__ void k_select(const float* __restrict__ scores, const float* __restrict__ Pq,
                         int* __restrict__ csel, float* __restrict__ mzLz,
                         float* __restrict__ out) {
    int b = blockIdx.x * blockDim.x + threadIdx.x;
    if (b >= B_N) return;

    float best = scores[b];
    int bc = 0;
    for (int k = 1; k < K_N; ++k) {
        float s = scores[(size_t)k * B_N + b];
        if (s > best) { best = s; bc = k; }
    }
    csel[b] = bc;
    out[OUT_PW + b] = 1.0f;

    float Pm[21], qv[6];
    const float* pq = Pq + (size_t)bc * 27 * B_N + b;
    #pragma unroll
    for (int t = 0; t < 21; ++t) Pm[t] = pq[(size_t)t * B_N];
    #pragma unroll
    for (int t = 0; t < 6; ++t) qv[t] = pq[(size_t)(21 + t) * B_N];

    float Lm[21], rd[6], dummy;
    chol6(Pm, Lm, rd, &dummy);

    // forward: L y = q
    float y[6];
    #pragma unroll
    for (int j = 0; j < 6; ++j) {
        float s = qv[j];
        #pragma unroll
        for (int m = 0; m < j; ++m) s -= Lm[IDX(j,m)] * y[m];
        y[j] = s * rd[j];
    }
    // backward: L^T mz = y
    float mz[6];
    #pragma unroll
    for (int ii = 5; ii >= 0; --ii) {
        float s = y[ii];
        #pragma unroll
        for (int j = ii + 1; j < 6; ++j) s -= Lm[IDX(j,ii)] * mz[j];
        mz[ii] = s * rd[ii];
    }
    // Linv (packed lower)
    float Li[21];
    #pragma unroll
    for (int j = 0; j < 6; ++j) {
        Li[IDX(j,j)] = rd[j];
        #pragma unroll
        for (int i = j + 1; i < 6; ++i) {
            float s = 0.f;
            #pragma unroll
            for (int m = j; m < i; ++m) s += Lm[IDX(i,m)] * Li[IDX(m,j)];
            Li[IDX(i,j)] = -s * rd[i];
        }
    }
    // cov = Linv^T Linv (packed lower)
    float cov[21];
    #pragma unroll
    for (int i = 0; i < 6; ++i) {
        #pragma unroll
        for (int j = 0; j <= i; ++j) {
            float s = 0.f;
            #pragma unroll
            for (int m = i; m < 6; ++m) s += Li[IDX(m,i)] * Li[IDX(m,j)];
            cov[IDX(i,j)] = s;
        }
    }
    float Lz[21], rd2[6];
    chol6(cov, Lz, rd2, &dummy);

    float* o = mzLz + (size_t)b * 28;
    #pragma unroll
    for (int t = 0; t < 6; ++t) o[t] = mz[t];
    #pragma unroll
    for (int t = 0; t < 21; ++t) o[6 + t] = Lz[t];
}

// ---------- KD: write M, A_out, D_out ----------
__global__ __launch_bounds__(256) void k_output(
        const float* __restrict__ A, const float* __restrict__ MU,
        const float* __restrict__ logD, const int* __restrict__ csel,
        const float* __restrict__ mzLz, float* __restrict__ out) {
    __shared__ float smz[6];
    __shared__ float sLz[21];
    __shared__ int sc;
    int b = blockIdx.x;
    if (threadIdx.x == 0) sc = csel[b];
    if (threadIdx.x < 27) {
        float v = mzLz[(size_t)b * 28 + threadIdx.x];
        if (threadIdx.x < 6) smz[threadIdx.x] = v;
        else sLz[threadIdx.x - 6] = v;
    }
    __syncthreads();
    int c = sc;

    for (int d = threadIdx.x; d < D_FT; d += 256) {
        const float* ar = A + ((size_t)c * D_FT + d) * 6;
        float a[6];
        #pragma unroll
        for (int i = 0; i < 6; ++i) a[i] = ar[i];
        float mu = MU[(size_t)c * D_FT + d];
        float ld = logD[(size_t)c * D_FT + d];
        float m = mu;
        #pragma unroll
        for (int i = 0; i < 6; ++i) m += a[i] * smz[i];
        out[OUT_M + (size_t)b * D_FT + d] = m;
        out[OUT_D + (size_t)b * D_FT + d] = expf(ld);
        float* ao = out + OUT_A + ((size_t)b * D_FT + d) * 6;
        #pragma unroll
        for (int j = 0; j < 6; ++j) {
            float s = 0.f;
            #pragma unroll
            for (int i = j; i < 6; ++i) s += a[i] * sLz[IDX(i,j)];
            ao[j] = s;
        }
    }
}

extern "C" void kernel_launch(void* const* d_in, const int* in_sizes, int n_in,
                              void* d_out, int out_size, void* d_ws, size_t ws_size,
                              hipStream_t stream) {
    (void)in_sizes; (void)n_in; (void)out_size; (void)ws_size;
    const float* X    = (const float*)d_in[0];
    const int*   J    = (const int*)d_in[1];
    const float* MU   = (const float*)d_in[2];
    const float* A    = (const float*)d_in[3];
    const float* logD = (const float*)d_in[4];
    const float* PI   = (const float*)d_in[5];
    float* out = (float*)d_out;
    float* ws  = (float*)d_ws;

    float*    scores = ws + WS_SCORES;
    float*    Pq     = ws + WS_PQ;
    int*      csel   = (int*)(ws + WS_C);
    float*    mzLz   = ws + WS_MZLZ;
    float4*   Xt4    = (float4*)(ws + WS_XT);
    unsigned* JbT    = (unsigned*)(ws + WS_JBT);

    dim3 g0((D_FT / 4 + 31) / 32, B_N / 32), b0(32, 32);
    k_transpose4<<<g0, b0, 0, stream>>>(X, Xt4);

    k_packbits<<<(B_N * 32) / 256, 256, 0, stream>>>(J, JbT);

    k_accum<<<16 * K_N, 512, 0, stream>>>(Xt4, JbT, A, MU, logD, PI, scores, Pq);

    k_select<<<B_N / 256, 256, 0, stream>>>(scores, Pq, csel, mzLz, out);

    k_output<<<B_N, 256, 0, stream>>>(A, MU, logD, csel, mzLz, out);
}

// Round 4
// 353.070 us; speedup vs baseline: 1.7360x; 1.7360x over previous
//
#include <hip/hip_runtime.h>
#include <math.h>

#define B_N 2048
#define D_FT 784
#define K_N 50
#define L_N 6
#define LOG2PI_F 1.8378770664093453f

// ---- output layout (floats), concatenated in reference return order ----
#define OUT_PW 0
#define OUT_M  (B_N)                              // 2048
#define OUT_A  (OUT_M + B_N*D_FT)                 // 1607680
#define OUT_D  (OUT_A + B_N*D_FT*6)               // 11241472

// ---- workspace layout (float offsets) ----
#define WS_SCORES 0                                // [K][B]  (also holds SJL pre-accum)
#define WS_PQ     (WS_SCORES + K_N*B_N)            // [K][27][B] 2764800
#define WS_C      (WS_PQ + K_N*27*B_N)             // [B] int    2048
#define WS_MZLZ   (WS_C + B_N)                     // [B][28]    57344
#define WS_XT     (WS_MZLZ + B_N*28)               // [D/4][B] float4 = D*B floats
#define WS_JBT    (WS_XT + D_FT*B_N)               // [25][B]    51200

#define IDX(i,j) ((i)*((i)+1)/2 + (j))   // packed lower, i>=j

// ---------- 6x6 packed-lower Cholesky ----------
__device__ __forceinline__ void chol6(const float* P, float* L, float* rd, float* sumlog) {
    float sl = 0.f;
    #pragma unroll
    for (int j = 0; j < 6; ++j) {
        float s = P[IDX(j,j)];
        #pragma unroll
        for (int m = 0; m < j; ++m) s -= L[IDX(j,m)] * L[IDX(j,m)];
        float d = sqrtf(s);
        L[IDX(j,j)] = d;
        float r = 1.0f / d;
        rd[j] = r;
        sl += logf(d);
        #pragma unroll
        for (int i = j + 1; i < 6; ++i) {
            float t = P[IDX(i,j)];
            #pragma unroll
            for (int m = 0; m < j; ++m) t -= L[IDX(i,m)] * L[IDX(j,m)];
            L[IDX(i,j)] = t * r;
        }
    }
    *sumlog = sl;
}

// ---------- K0: transpose X [B][D] -> Xt4 [D/4][B] (float4 per cell) ----------
__global__ __launch_bounds__(1024) void k_transpose4(const float* __restrict__ X,
                                                     float4* __restrict__ Xt4) {
    __shared__ float4 tile[32][33];
    int tx = threadIdx.x, ty = threadIdx.y;
    int d4b = blockIdx.x * 32;
    int bb  = blockIdx.y * 32;
    int d4 = d4b + tx;
    if (d4 < D_FT / 4)
        tile[ty][tx] = *(const float4*)&X[(size_t)(bb + ty) * D_FT + d4 * 4];
    __syncthreads();
    int d4o = d4b + ty;
    if (d4o < D_FT / 4)
        Xt4[(size_t)d4o * B_N + (bb + tx)] = tile[tx][ty];
}

// ---------- K0b: pack J bits -> JbT[w][b], w in [0,25) ----------
__global__ void k_packbits(const int* __restrict__ J, unsigned* __restrict__ JbT) {
    int t = blockIdx.x * blockDim.x + threadIdx.x;   // 2048*32 threads
    int b = t >> 5;
    int w = t & 31;
    if (w >= 25) return;
    int d0 = w * 32;
    int n = D_FT - d0; if (n > 32) n = 32;
    unsigned u = 0;
    for (int j = 0; j < n; ++j)
        u |= (J[(size_t)b * D_FT + d0 + j] != 0 ? 1u : 0u) << j;
    JbT[(size_t)w * B_N + b] = u;
}

// ---------- K0c: SJL[k][b] = sum_d Jf[b,d]*logD[k,d]  (into scores buffer) ----------
__global__ __launch_bounds__(256) void k_jld(const float* __restrict__ logD,
                                             const unsigned* __restrict__ JbT,
                                             float* __restrict__ SJL) {
    __shared__ float ld[800];
    const int k  = blockIdx.x >> 3;
    const int bt = blockIdx.x & 7;
    for (int i = threadIdx.x; i < 800; i += 256)
        ld[i] = (i < D_FT) ? logD[(size_t)k * D_FT + i] : 0.f;
    __syncthreads();
    const int b = bt * 256 + threadIdx.x;
    float jl = 0.f;
    for (int w = 0; w < 25; ++w) {
        unsigned mw = JbT[(size_t)w * B_N + b];
        const float* lw = &ld[w * 32];
        #pragma unroll
        for (int dd = 0; dd < 32; ++dd)
            jl += ((mw >> dd) & 1u) ? lw[dd] : 0.f;
    }
    SJL[(size_t)k * B_N + b] = jl;
}

// ---------- K1: per-(sample,k) accumulation + loglik ----------
// 256 threads = 64 samples x 4 d-quarters. quarter h covers words h*6..h*6+5
// (h==3: also 16-bit tail word 24). Record: [a0..a5, invD, mu] = 32B -> 2x b128.
#define ACC_BODY(dd, xval) do { \
    const int d_ = wbase + (dd); \
    const float4 ra = *(const float4*)&smem[d_ * 8]; \
    const float4 rb = *(const float4*)&smem[d_ * 8 + 4]; \
    const bool ob = ((mw >> (dd)) & 1u) != 0u; \
    float giD = ob ? rb.z : 0.f; \
    float xm = (xval) - rb.w; \
    float md = ob ? xm : 0.f; \
    float u0=giD*ra.x, u1=giD*ra.y, u2=giD*ra.z, u3=giD*ra.w, u4=giD*rb.x, u5=giD*rb.y; \
    Pm[0]  += u0*ra.x; \
    Pm[1]  += u1*ra.x; Pm[2]  += u1*ra.y; \
    Pm[3]  += u2*ra.x; Pm[4]  += u2*ra.y; Pm[5]  += u2*ra.z; \
    Pm[6]  += u3*ra.x; Pm[7]  += u3*ra.y; Pm[8]  += u3*ra.z; Pm[9]  += u3*ra.w; \
    Pm[10] += u4*ra.x; Pm[11] += u4*ra.y; Pm[12] += u4*ra.z; Pm[13] += u4*ra.w; Pm[14] += u4*rb.x; \
    Pm[15] += u5*ra.x; Pm[16] += u5*ra.y; Pm[17] += u5*ra.z; Pm[18] += u5*ra.w; Pm[19] += u5*rb.x; Pm[20] += u5*rb.y; \
    qv[0] += md*u0; qv[1] += md*u1; qv[2] += md*u2; \
    qv[3] += md*u3; qv[4] += md*u4; qv[5] += md*u5; \
    float tq = md * md; \
    quad += tq * giD; \
} while (0)

__global__ __launch_bounds__(256, 6) void k_accum(
        const float4* __restrict__ Xt4, const unsigned* __restrict__ JbT,
        const float* __restrict__ A, const float* __restrict__ MU,
        const float* __restrict__ logD, const float* __restrict__ PI,
        float* __restrict__ scores, float* __restrict__ Pq) {
    __shared__ float4 smem4[D_FT * 2];   // 25088 B; aliased as reduction buffer later
    float* smem = (float*)smem4;
    const int k   = blockIdx.x >> 5;
    const int tid = threadIdx.x;
    const int s   = tid & 63;
    const int h   = tid >> 6;           // d-quarter 0..3
    const int b   = (blockIdx.x & 31) * 64 + s;

    for (int i = tid; i < D_FT; i += 256) {
        const float* ar = A + ((size_t)k * D_FT + i) * 6;
        float* r = &smem[i * 8];
        r[0]=ar[0]; r[1]=ar[1]; r[2]=ar[2]; r[3]=ar[3]; r[4]=ar[4]; r[5]=ar[5];
        r[6] = expf(-logD[(size_t)k * D_FT + i]);
        r[7] = MU[(size_t)k * D_FT + i];
    }
    __syncthreads();

    float Pm[21], qv[6];
    #pragma unroll
    for (int t = 0; t < 21; ++t) Pm[t] = 0.f;
    #pragma unroll
    for (int t = 0; t < 6; ++t) qv[t] = 0.f;
    float quad = 0.f;
    int nob = 0;

    const int w0 = h * 6;
    const int w1 = w0 + 6;              // h==3: words 18..23 full, word 24 tail below
    for (int w = w0; w < w1; ++w) {
        const unsigned mw = JbT[(size_t)w * B_N + b];
        nob += __popc(mw);
        const int wbase = w * 32;
        const float4* xp = Xt4 + (size_t)(w * 8) * B_N + b;
        #pragma unroll 4
        for (int g = 0; g < 8; ++g) {
            float4 xv = xp[(size_t)g * B_N];
            ACC_BODY(g * 4 + 0, xv.x);
            ACC_BODY(g * 4 + 1, xv.y);
            ACC_BODY(g * 4 + 2, xv.z);
            ACC_BODY(g * 4 + 3, xv.w);
        }
    }
    if (h == 3) {  // tail word 24: bits 0..15 valid (packed zeros above)
        const unsigned mw = JbT[(size_t)24 * B_N + b];
        nob += __popc(mw);
        const int wbase = 768;
        const float4* xp = Xt4 + (size_t)(24 * 8) * B_N + b;
        #pragma unroll
        for (int g = 0; g < 4; ++g) {
            float4 xv = xp[(size_t)g * B_N];
            ACC_BODY(g * 4 + 0, xv.x);
            ACC_BODY(g * 4 + 1, xv.y);
            ACC_BODY(g * 4 + 2, xv.z);
            ACC_BODY(g * 4 + 3, xv.w);
        }
    }

    // merge the 4 d-quarters through LDS (staging buffer is dead now).
    // slabs: 64 samples x 33 floats, conflict-free (33 % 32 == 1).
    __syncthreads();
    float* red = smem;
    if (h & 1) {
        float* o = &red[(size_t)(h >> 1) * (64 * 33) + s * 33];
        #pragma unroll
        for (int t = 0; t < 21; ++t) o[t] = Pm[t];
        #pragma unroll
        for (int t = 0; t < 6; ++t) o[21 + t] = qv[t];
        o[27] = quad; o[28] = (float)nob;
    }
    __syncthreads();
    if (!(h & 1)) {
        const float* o = &red[(size_t)(h >> 1) * (64 * 33) + s * 33];
        #pragma unroll
        for (int t = 0; t < 21; ++t) Pm[t] += o[t];
        #pragma unroll
        for (int t = 0; t < 6; ++t) qv[t] += o[21 + t];
        quad += o[27]; nob += (int)o[28];
    }
    __syncthreads();
    if (h == 2) {
        float* o = &red[s * 33];
        #pragma unroll
        for (int t = 0; t < 21; ++t) o[t] = Pm[t];
        #pragma unroll
        for (int t = 0; t < 6; ++t) o[21 + t] = qv[t];
        o[27] = quad; o[28] = (float)nob;
    }
    __syncthreads();
    if (h == 0) {
        const float* o = &red[s * 33];
        #pragma unroll
        for (int t = 0; t < 21; ++t) Pm[t] += o[t];
        #pragma unroll
        for (int t = 0; t < 6; ++t) qv[t] += o[21 + t];
        quad += o[27];
        float nobs = (float)(nob + (int)o[28]);

        // jld precomputed by k_jld into the scores buffer (read before overwrite)
        float jld = scores[(size_t)k * B_N + b];

        // P = I + sum
        Pm[0] += 1.f; Pm[2] += 1.f; Pm[5] += 1.f; Pm[9] += 1.f; Pm[14] += 1.f; Pm[20] += 1.f;

        float Lm[21], rd[6], sumlog;
        chol6(Pm, Lm, rd, &sumlog);
        float y[6];
        #pragma unroll
        for (int j = 0; j < 6; ++j) {
            float sv = qv[j];
            #pragma unroll
            for (int m = 0; m < j; ++m) sv -= Lm[IDX(j,m)] * y[m];
            y[j] = sv * rd[j];
        }
        float yy = 0.f;
        #pragma unroll
        for (int j = 0; j < 6; ++j) yy += y[j] * y[j];
        float logdet = 2.f * sumlog + jld;
        float ll = -0.5f * ((quad - yy) + logdet + nobs * LOG2PI_F);
        float score = ll + PI[k];

        scores[(size_t)k * B_N + b] = score;
        float* pq = Pq + (size_t)k * 27 * B_N + b;
        #pragma unroll
        for (int t = 0; t < 21; ++t) pq[(size_t)t * B_N] = Pm[t];
        #pragma unroll
        for (int t = 0; t < 6; ++t) pq[(size_t)(21 + t) * B_N] = qv[t];
    }
}

// ---------- KC: argmax + latent solve per sample ----------
__global__ void k_select(const float* __restrict__ scores, const float* __restrict__ Pq,
                         int* __restrict__ csel, float* __restrict__ mzLz,
                         float* __restrict__ out) {
    int b = blockIdx.x * blockDim.x + threadIdx.x;
    if (b >= B_N) return;

    float best = scores[b];
    int bc = 0;
    for (int k = 1; k < K_N; ++k) {
        float s = scores[(size_t)k * B_N + b];
        if (s > best) { best = s; bc = k; }
    }
    csel[b] = bc;
    out[OUT_PW + b] = 1.0f;

    float Pm[21], qv[6];
    const float* pq = Pq + (size_t)bc * 27 * B_N + b;
    #pragma unroll
    for (int t = 0; t < 21; ++t) Pm[t] = pq[(size_t)t * B_N];
    #pragma unroll
    for (int t = 0; t < 6; ++t) qv[t] = pq[(size_t)(21 + t) * B_N];

    float Lm[21], rd[6], dummy;
    chol6(Pm, Lm, rd, &dummy);

    // forward: L y = q
    float y[6];
    #pragma unroll
    for (int j = 0; j < 6; ++j) {
        float s = qv[j];
        #pragma unroll
        for (int m = 0; m < j; ++m) s -= Lm[IDX(j,m)] * y[m];
        y[j] = s * rd[j];
    }
    // backward: L^T mz = y
    float mz[6];
    #pragma unroll
    for (int ii = 5; ii >= 0; --ii) {
        float s = y[ii];
        #pragma unroll
        for (int j = ii + 1; j < 6; ++j) s -= Lm[IDX(j,ii)] * mz[j];
        mz[ii] = s * rd[ii];
    }
    // Linv (packed lower)
    float Li[21];
    #pragma unroll
    for (int j = 0; j < 6; ++j) {
        Li[IDX(j,j)] = rd[j];
        #pragma unroll
        for (int i = j + 1; i < 6; ++i) {
            float s = 0.f;
            #pragma unroll
            for (int m = j; m < i; ++m) s += Lm[IDX(i,m)] * Li[IDX(m,j)];
            Li[IDX(i,j)] = -s * rd[i];
        }
    }
    // cov = Linv^T Linv (packed lower)
    float cov[21];
    #pragma unroll
    for (int i = 0; i < 6; ++i) {
        #pragma unroll
        for (int j = 0; j <= i; ++j) {
            float s = 0.f;
            #pragma unroll
            for (int m = i; m < 6; ++m) s += Li[IDX(m,i)] * Li[IDX(m,j)];
            cov[IDX(i,j)] = s;
        }
    }
    float Lz[21], rd2[6];
    chol6(cov, Lz, rd2, &dummy);

    float* o = mzLz + (size_t)b * 28;
    #pragma unroll
    for (int t = 0; t < 6; ++t) o[t] = mz[t];
    #pragma unroll
    for (int t = 0; t < 21; ++t) o[6 + t] = Lz[t];
}

// ---------- KD: write M, A_out, D_out ----------
__global__ __launch_bounds__(256) void k_output(
        const float* __restrict__ A, const float* __restrict__ MU,
        const float* __restrict__ logD, const int* __restrict__ csel,
        const float* __restrict__ mzLz, float* __restrict__ out) {
    __shared__ float smz[6];
    __shared__ float sLz[21];
    __shared__ int sc;
    int b = blockIdx.x;
    if (threadIdx.x == 0) sc = csel[b];
    if (threadIdx.x < 27) {
        float v = mzLz[(size_t)b * 28 + threadIdx.x];
        if (threadIdx.x < 6) smz[threadIdx.x] = v;
        else sLz[threadIdx.x - 6] = v;
    }
    __syncthreads();
    int c = sc;

    for (int d = threadIdx.x; d < D_FT; d += 256) {
        const float* ar = A + ((size_t)c * D_FT + d) * 6;
        float a[6];
        #pragma unroll
        for (int i = 0; i < 6; ++i) a[i] = ar[i];
        float mu = MU[(size_t)c * D_FT + d];
        float ld = logD[(size_t)c * D_FT + d];
        float m = mu;
        #pragma unroll
        for (int i = 0; i < 6; ++i) m += a[i] * smz[i];
        out[OUT_M + (size_t)b * D_FT + d] = m;
        out[OUT_D + (size_t)b * D_FT + d] = expf(ld);
        float* ao = out + OUT_A + ((size_t)b * D_FT + d) * 6;
        #pragma unroll
        for (int j = 0; j < 6; ++j) {
            float s = 0.f;
            #pragma unroll
            for (int i = j; i < 6; ++i) s += a[i] * sLz[IDX(i,j)];
            ao[j] = s;
        }
    }
}

extern "C" void kernel_launch(void* const* d_in, const int* in_sizes, int n_in,
                              void* d_out, int out_size, void* d_ws, size_t ws_size,
                              hipStream_t stream) {
    (void)in_sizes; (void)n_in; (void)out_size; (void)ws_size;
    const float* X    = (const float*)d_in[0];
    const int*   J    = (const int*)d_in[1];
    const float* MU   = (const float*)d_in[2];
    const float* A    = (const float*)d_in[3];
    const float* logD = (const float*)d_in[4];
    const float* PI   = (const float*)d_in[5];
    float* out = (float*)d_out;
    float* ws  = (float*)d_ws;

    float*    scores = ws + WS_SCORES;   // pre-accum: SJL (jld terms)
    float*    Pq     = ws + WS_PQ;
    int*      csel   = (int*)(ws + WS_C);
    float*    mzLz   = ws + WS_MZLZ;
    float4*   Xt4    = (float4*)(ws + WS_XT);
    unsigned* JbT    = (unsigned*)(ws + WS_JBT);

    dim3 g0((D_FT / 4 + 31) / 32, B_N / 32), b0(32, 32);
    k_transpose4<<<g0, b0, 0, stream>>>(X, Xt4);

    k_packbits<<<(B_N * 32) / 256, 256, 0, stream>>>(J, JbT);

    k_jld<<<K_N * 8, 256, 0, stream>>>(logD, JbT, scores);

    k_accum<<<32 * K_N, 256, 0, stream>>>(Xt4, JbT, A, MU, logD, PI, scores, Pq);

    k_select<<<B_N / 256, 256, 0, stream>>>(scores, Pq, csel, mzLz, out);

    k_output<<<B_N, 256, 0, stream>>>(A, MU, logD, csel, mzLz, out);
}

// Round 5
// 163.373 us; speedup vs baseline: 3.7518x; 2.1611x over previous
//
#include <hip/hip_runtime.h>
#include <math.h>

#define B_N 2048
#define D_FT 784
#define K_N 50
#define L_N 6
#define LOG2PI_F 1.8378770664093453f

// ---- output layout (floats), concatenated in reference return order ----
#define OUT_PW 0
#define OUT_M  (B_N)                              // 2048
#define OUT_A  (OUT_M + B_N*D_FT)                 // 1607680
#define OUT_D  (OUT_A + B_N*D_FT*6)               // 11241472

// ---- workspace layout (float offsets) ----
#define WS_SCORES 0                                // [K][B]  (also holds SJL pre-accum)
#define WS_PQ     (WS_SCORES + K_N*B_N)            // [K][27][B] 2764800
#define WS_C      (WS_PQ + K_N*27*B_N)             // [B] int    2048
#define WS_MZLZ   (WS_C + B_N)                     // [B][28]    57344
#define WS_XT     (WS_MZLZ + B_N*28)               // [D/4][B] float4 = D*B floats
#define WS_JBT    (WS_XT + D_FT*B_N)               // [25][B]    51200

#define IDX(i,j) ((i)*((i)+1)/2 + (j))   // packed lower, i>=j

// ---------- 6x6 packed-lower Cholesky ----------
__device__ __forceinline__ void chol6(const float* P, float* L, float* rd, float* sumlog) {
    float sl = 0.f;
    #pragma unroll
    for (int j = 0; j < 6; ++j) {
        float s = P[IDX(j,j)];
        #pragma unroll
        for (int m = 0; m < j; ++m) s -= L[IDX(j,m)] * L[IDX(j,m)];
        float d = sqrtf(s);
        L[IDX(j,j)] = d;
        float r = 1.0f / d;
        rd[j] = r;
        sl += logf(d);
        #pragma unroll
        for (int i = j + 1; i < 6; ++i) {
            float t = P[IDX(i,j)];
            #pragma unroll
            for (int m = 0; m < j; ++m) t -= L[IDX(i,m)] * L[IDX(j,m)];
            L[IDX(i,j)] = t * r;
        }
    }
    *sumlog = sl;
}

// ---------- K0: transpose X [B][D] -> Xt4 [D/4][B] (float4 per cell) ----------
__global__ __launch_bounds__(1024) void k_transpose4(const float* __restrict__ X,
                                                     float4* __restrict__ Xt4) {
    __shared__ float4 tile[32][33];
    int tx = threadIdx.x, ty = threadIdx.y;
    int d4b = blockIdx.x * 32;
    int bb  = blockIdx.y * 32;
    int d4 = d4b + tx;
    if (d4 < D_FT / 4)
        tile[ty][tx] = *(const float4*)&X[(size_t)(bb + ty) * D_FT + d4 * 4];
    __syncthreads();
    int d4o = d4b + ty;
    if (d4o < D_FT / 4)
        Xt4[(size_t)d4o * B_N + (bb + tx)] = tile[tx][ty];
}

// ---------- K0b: pack J bits -> JbT[w][b], w in [0,25) ----------
__global__ void k_packbits(const int* __restrict__ J, unsigned* __restrict__ JbT) {
    int t = blockIdx.x * blockDim.x + threadIdx.x;   // 2048*32 threads
    int b = t >> 5;
    int w = t & 31;
    if (w >= 25) return;
    int d0 = w * 32;
    int n = D_FT - d0; if (n > 32) n = 32;
    unsigned u = 0;
    for (int j = 0; j < n; ++j)
        u |= (J[(size_t)b * D_FT + d0 + j] != 0 ? 1u : 0u) << j;
    JbT[(size_t)w * B_N + b] = u;
}

// ---------- K0c: SJL[k][b] = sum_d Jf[b,d]*logD[k,d]  (into scores buffer) ----------
__global__ __launch_bounds__(256) void k_jld(const float* __restrict__ logD,
                                             const unsigned* __restrict__ JbT,
                                             float* __restrict__ SJL) {
    __shared__ float ld[800];
    const int k  = blockIdx.x >> 3;
    const int bt = blockIdx.x & 7;
    for (int i = threadIdx.x; i < 800; i += 256)
        ld[i] = (i < D_FT) ? logD[(size_t)k * D_FT + i] : 0.f;
    __syncthreads();
    const int b = bt * 256 + threadIdx.x;
    float jl = 0.f;
    for (int w = 0; w < 25; ++w) {
        unsigned mw = JbT[(size_t)w * B_N + b];
        const float* lw = &ld[w * 32];
        #pragma unroll
        for (int dd = 0; dd < 32; ++dd)
            jl += ((mw >> dd) & 1u) ? lw[dd] : 0.f;
    }
    SJL[(size_t)k * B_N + b] = jl;
}

// ---------- K1: per-(sample,k) accumulation + loglik ----------
// 256 threads = 64 samples x 4 d-quarters. quarter h covers words h*6..h*6+5
// (h==3: also 16-bit tail word 24). Record: [a0..a5, invD, mu] = 32B -> 2x b128.
// NOTE: launch_bounds MUST stay (256,4): min-waves>=6 makes the allocator
// pick a spill schedule (r3: 32 VGPR/1.5GB scratch; r4: 40 VGPR/635MB).
#define ACC_BODY(dd, xval) do { \
    const int d_ = wbase + (dd); \
    const float4 ra = *(const float4*)&smem[d_ * 8]; \
    const float4 rb = *(const float4*)&smem[d_ * 8 + 4]; \
    const bool ob = ((mw >> (dd)) & 1u) != 0u; \
    float giD = ob ? rb.z : 0.f; \
    float xm = (xval) - rb.w; \
    float md = ob ? xm : 0.f; \
    float u0=giD*ra.x, u1=giD*ra.y, u2=giD*ra.z, u3=giD*ra.w, u4=giD*rb.x, u5=giD*rb.y; \
    Pm[0]  += u0*ra.x; \
    Pm[1]  += u1*ra.x; Pm[2]  += u1*ra.y; \
    Pm[3]  += u2*ra.x; Pm[4]  += u2*ra.y; Pm[5]  += u2*ra.z; \
    Pm[6]  += u3*ra.x; Pm[7]  += u3*ra.y; Pm[8]  += u3*ra.z; Pm[9]  += u3*ra.w; \
    Pm[10] += u4*ra.x; Pm[11] += u4*ra.y; Pm[12] += u4*ra.z; Pm[13] += u4*ra.w; Pm[14] += u4*rb.x; \
    Pm[15] += u5*ra.x; Pm[16] += u5*ra.y; Pm[17] += u5*ra.z; Pm[18] += u5*ra.w; Pm[19] += u5*rb.x; Pm[20] += u5*rb.y; \
    qv[0] += md*u0; qv[1] += md*u1; qv[2] += md*u2; \
    qv[3] += md*u3; qv[4] += md*u4; qv[5] += md*u5; \
    float tq = md * md; \
    quad += tq * giD; \
} while (0)

__global__ __launch_bounds__(256, 4) void k_accum(
        const float4* __restrict__ Xt4, const unsigned* __restrict__ JbT,
        const float* __restrict__ A, const float* __restrict__ MU,
        const float* __restrict__ logD, const float* __restrict__ PI,
        float* __restrict__ scores, float* __restrict__ Pq) {
    __shared__ float4 smem4[D_FT * 2];   // 25088 B; aliased as reduction buffer later
    float* smem = (float*)smem4;
    const int k   = blockIdx.x >> 5;
    const int tid = threadIdx.x;
    const int s   = tid & 63;
    const int h   = tid >> 6;           // d-quarter 0..3
    const int b   = (blockIdx.x & 31) * 64 + s;

    for (int i = tid; i < D_FT; i += 256) {
        const float* ar = A + ((size_t)k * D_FT + i) * 6;
        float* r = &smem[i * 8];
        r[0]=ar[0]; r[1]=ar[1]; r[2]=ar[2]; r[3]=ar[3]; r[4]=ar[4]; r[5]=ar[5];
        r[6] = expf(-logD[(size_t)k * D_FT + i]);
        r[7] = MU[(size_t)k * D_FT + i];
    }
    __syncthreads();

    float Pm[21], qv[6];
    #pragma unroll
    for (int t = 0; t < 21; ++t) Pm[t] = 0.f;
    #pragma unroll
    for (int t = 0; t < 6; ++t) qv[t] = 0.f;
    float quad = 0.f;
    int nob = 0;

    const int w0 = h * 6;
    const int w1 = w0 + 6;              // h==3: words 18..23 full, word 24 tail below
    for (int w = w0; w < w1; ++w) {
        const unsigned mw = JbT[(size_t)w * B_N + b];
        nob += __popc(mw);
        const int wbase = w * 32;
        const float4* xp = Xt4 + (size_t)(w * 8) * B_N + b;
        #pragma unroll 4
        for (int g = 0; g < 8; ++g) {
            float4 xv = xp[(size_t)g * B_N];
            ACC_BODY(g * 4 + 0, xv.x);
            ACC_BODY(g * 4 + 1, xv.y);
            ACC_BODY(g * 4 + 2, xv.z);
            ACC_BODY(g * 4 + 3, xv.w);
        }
    }
    if (h == 3) {  // tail word 24: bits 0..15 valid (packed zeros above)
        const unsigned mw = JbT[(size_t)24 * B_N + b];
        nob += __popc(mw);
        const int wbase = 768;
        const float4* xp = Xt4 + (size_t)(24 * 8) * B_N + b;
        #pragma unroll
        for (int g = 0; g < 4; ++g) {
            float4 xv = xp[(size_t)g * B_N];
            ACC_BODY(g * 4 + 0, xv.x);
            ACC_BODY(g * 4 + 1, xv.y);
            ACC_BODY(g * 4 + 2, xv.z);
            ACC_BODY(g * 4 + 3, xv.w);
        }
    }

    // merge the 4 d-quarters through LDS (staging buffer is dead now).
    // slabs: 64 samples x 33 floats, conflict-free (33 % 32 == 1).
    __syncthreads();
    float* red = smem;
    if (h & 1) {
        float* o = &red[(size_t)(h >> 1) * (64 * 33) + s * 33];
        #pragma unroll
        for (int t = 0; t < 21; ++t) o[t] = Pm[t];
        #pragma unroll
        for (int t = 0; t < 6; ++t) o[21 + t] = qv[t];
        o[27] = quad; o[28] = (float)nob;
    }
    __syncthreads();
    if (!(h & 1)) {
        const float* o = &red[(size_t)(h >> 1) * (64 * 33) + s * 33];
        #pragma unroll
        for (int t = 0; t < 21; ++t) Pm[t] += o[t];
        #pragma unroll
        for (int t = 0; t < 6; ++t) qv[t] += o[21 + t];
        quad += o[27]; nob += (int)o[28];
    }
    __syncthreads();
    if (h == 2) {
        float* o = &red[s * 33];
        #pragma unroll
        for (int t = 0; t < 21; ++t) o[t] = Pm[t];
        #pragma unroll
        for (int t = 0; t < 6; ++t) o[21 + t] = qv[t];
        o[27] = quad; o[28] = (float)nob;
    }
    __syncthreads();
    if (h == 0) {
        const float* o = &red[s * 33];
        #pragma unroll
        for (int t = 0; t < 21; ++t) Pm[t] += o[t];
        #pragma unroll
        for (int t = 0; t < 6; ++t) qv[t] += o[21 + t];
        quad += o[27];
        float nobs = (float)(nob + (int)o[28]);

        // jld precomputed by k_jld into the scores buffer (read before overwrite)
        float jld = scores[(size_t)k * B_N + b];

        // P = I + sum
        Pm[0] += 1.f; Pm[2] += 1.f; Pm[5] += 1.f; Pm[9] += 1.f; Pm[14] += 1.f; Pm[20] += 1.f;

        float Lm[21], rd[6], sumlog;
        chol6(Pm, Lm, rd, &sumlog);
        float y[6];
        #pragma unroll
        for (int j = 0; j < 6; ++j) {
            float sv = qv[j];
            #pragma unroll
            for (int m = 0; m < j; ++m) sv -= Lm[IDX(j,m)] * y[m];
            y[j] = sv * rd[j];
        }
        float yy = 0.f;
        #pragma unroll
        for (int j = 0; j < 6; ++j) yy += y[j] * y[j];
        float logdet = 2.f * sumlog + jld;
        float ll = -0.5f * ((quad - yy) + logdet + nobs * LOG2PI_F);
        float score = ll + PI[k];

        scores[(size_t)k * B_N + b] = score;
        float* pq = Pq + (size_t)k * 27 * B_N + b;
        #pragma unroll
        for (int t = 0; t < 21; ++t) pq[(size_t)t * B_N] = Pm[t];
        #pragma unroll
        for (int t = 0; t < 6; ++t) pq[(size_t)(21 + t) * B_N] = qv[t];
    }
}

// ---------- KC: argmax + latent solve per sample ----------
__global__ void k_select(const float* __restrict__ scores, const float* __restrict__ Pq,
                         int* __restrict__ csel, float* __restrict__ mzLz,
                         float* __restrict__ out) {
    int b = blockIdx.x * blockDim.x + threadIdx.x;
    if (b >= B_N) return;

    float best = scores[b];
    int bc = 0;
    for (int k = 1; k < K_N; ++k) {
        float s = scores[(size_t)k * B_N + b];
        if (s > best) { best = s; bc = k; }
    }
    csel[b] = bc;
    out[OUT_PW + b] = 1.0f;

    float Pm[21], qv[6];
    const float* pq = Pq + (size_t)bc * 27 * B_N + b;
    #pragma unroll
    for (int t = 0; t < 21; ++t) Pm[t] = pq[(size_t)t * B_N];
    #pragma unroll
    for (int t = 0; t < 6; ++t) qv[t] = pq[(size_t)(21 + t) * B_N];

    float Lm[21], rd[6], dummy;
    chol6(Pm, Lm, rd, &dummy);

    // forward: L y = q
    float y[6];
    #pragma unroll
    for (int j = 0; j < 6; ++j) {
        float s = qv[j];
        #pragma unroll
        for (int m = 0; m < j; ++m) s -= Lm[IDX(j,m)] * y[m];
        y[j] = s * rd[j];
    }
    // backward: L^T mz = y
    float mz[6];
    #pragma unroll
    for (int ii = 5; ii >= 0; --ii) {
        float s = y[ii];
        #pragma unroll
        for (int j = ii + 1; j < 6; ++j) s -= Lm[IDX(j,ii)] * mz[j];
        mz[ii] = s * rd[ii];
    }
    // Linv (packed lower)
    float Li[21];
    #pragma unroll
    for (int j = 0; j < 6; ++j) {
        Li[IDX(j,j)] = rd[j];
        #pragma unroll
        for (int i = j + 1; i < 6; ++i) {
            float s = 0.f;
            #pragma unroll
            for (int m = j; m < i; ++m) s += Lm[IDX(i,m)] * Li[IDX(m,j)];
            Li[IDX(i,j)] = -s * rd[i];
        }
    }
    // cov = Linv^T Linv (packed lower)
    float cov[21];
    #pragma unroll
    for (int i = 0; i < 6; ++i) {
        #pragma unroll
        for (int j = 0; j <= i; ++j) {
            float s = 0.f;
            #pragma unroll
            for (int m = i; m < 6; ++m) s += Li[IDX(m,i)] * Li[IDX(m,j)];
            cov[IDX(i,j)] = s;
        }
    }
    float Lz[21], rd2[6];
    chol6(cov, Lz, rd2, &dummy);

    float* o = mzLz + (size_t)b * 28;
    #pragma unroll
    for (int t = 0; t < 6; ++t) o[t] = mz[t];
    #pragma unroll
    for (int t = 0; t < 21; ++t) o[6 + t] = Lz[t];
}

// ---------- KD: write M, A_out, D_out ----------
__global__ __launch_bounds__(256) void k_output(
        const float* __restrict__ A, const float* __restrict__ MU,
        const float* __restrict__ logD, const int* __restrict__ csel,
        const float* __restrict__ mzLz, float* __restrict__ out) {
    __shared__ float smz[6];
    __shared__ float sLz[21];
    __shared__ int sc;
    int b = blockIdx.x;
    if (threadIdx.x == 0) sc = csel[b];
    if (threadIdx.x < 27) {
        float v = mzLz[(size_t)b * 28 + threadIdx.x];
        if (threadIdx.x < 6) smz[threadIdx.x] = v;
        else sLz[threadIdx.x - 6] = v;
    }
    __syncthreads();
    int c = sc;

    for (int d = threadIdx.x; d < D_FT; d += 256) {
        const float* ar = A + ((size_t)c * D_FT + d) * 6;
        float a[6];
        #pragma unroll
        for (int i = 0; i < 6; ++i) a[i] = ar[i];
        float mu = MU[(size_t)c * D_FT + d];
        float ld = logD[(size_t)c * D_FT + d];
        float m = mu;
        #pragma unroll
        for (int i = 0; i < 6; ++i) m += a[i] * smz[i];
        out[OUT_M + (size_t)b * D_FT + d] = m;
        out[OUT_D + (size_t)b * D_FT + d] = expf(ld);
        float* ao = out + OUT_A + ((size_t)b * D_FT + d) * 6;
        #pragma unroll
        for (int j = 0; j < 6; ++j) {
            float s = 0.f;
            #pragma unroll
            for (int i = j; i < 6; ++i) s += a[i] * sLz[IDX(i,j)];
            ao[j] = s;
        }
    }
}

extern "C" void kernel_launch(void* const* d_in, const int* in_sizes, int n_in,
                              void* d_out, int out_size, void* d_ws, size_t ws_size,
                              hipStream_t stream) {
    (void)in_sizes; (void)n_in; (void)out_size; (void)ws_size;
    const float* X    = (const float*)d_in[0];
    const int*   J    = (const int*)d_in[1];
    const float* MU   = (const float*)d_in[2];
    const float* A    = (const float*)d_in[3];
    const float* logD = (const float*)d_in[4];
    const float* PI   = (const float*)d_in[5];
    float* out = (float*)d_out;
    float* ws  = (float*)d_ws;

    float*    scores = ws + WS_SCORES;   // pre-accum: SJL (jld terms)
    float*    Pq     = ws + WS_PQ;
    int*      csel   = (int*)(ws + WS_C);
    float*    mzLz   = ws + WS_MZLZ;
    float4*   Xt4    = (float4*)(ws + WS_XT);
    unsigned* JbT    = (unsigned*)(ws + WS_JBT);

    dim3 g0((D_FT / 4 + 31) / 32, B_N / 32), b0(32, 32);
    k_transpose4<<<g0, b0, 0, stream>>>(X, Xt4);

    k_packbits<<<(B_N * 32) / 256, 256, 0, stream>>>(J, JbT);

    k_jld<<<K_N * 8, 256, 0, stream>>>(logD, JbT, scores);

    k_accum<<<32 * K_N, 256, 0, stream>>>(Xt4, JbT, A, MU, logD, PI, scores, Pq);

    k_select<<<B_N / 256, 256, 0, stream>>>(scores, Pq, csel, mzLz, out);

    k_output<<<B_N, 256, 0, stream>>>(A, MU, logD, csel, mzLz, out);
}

// Round 6
// 139.030 us; speedup vs baseline: 4.4087x; 1.1751x over previous
//
#include <hip/hip_runtime.h>
#include <math.h>

#define B_N 2048
#define D_FT 784
#define K_N 50
#define L_N 6
#define LOG2PI_F 1.8378770664093453f

// ---- output layout (floats), concatenated in reference return order ----
#define OUT_PW 0
#define OUT_M  (B_N)                              // 2048
#define OUT_A  (OUT_M + B_N*D_FT)                 // 1607680
#define OUT_D  (OUT_A + B_N*D_FT*6)               // 11241472

// ---- workspace layout (float offsets) ----
#define WS_SCORES 0                                // [K][B]  (also holds SJL pre-accum)
#define WS_PQ     (WS_SCORES + K_N*B_N)            // [K][27][B] 2764800
#define WS_C      (WS_PQ + K_N*27*B_N)             // [B] int    2048
#define WS_MZLZ   (WS_C + B_N)                     // [B][28]    57344
#define WS_XT     (WS_MZLZ + B_N*28)               // [D/4][B] float4 = D*B floats
#define WS_JBT    (WS_XT + D_FT*B_N)               // [25][B]    51200

#define IDX(i,j) ((i)*((i)+1)/2 + (j))   // packed lower, i>=j

typedef float v2f __attribute__((ext_vector_type(2)));

// VOP3P packed f32 ops (CDNA2+; the 157 TF fp32 spec is this packed rate).
#define PK_FMA(acc, a, b) asm("v_pk_fma_f32 %0, %1, %2, %0" : "+v"(acc) : "v"(a), "v"(b))
#define PK_MUL(dst, a, b) asm("v_pk_mul_f32 %0, %1, %2" : "=v"(dst) : "v"(a), "v"(b))
#define PK_ADD(dst, a, b) asm("v_pk_add_f32 %0, %1, %2" : "=v"(dst) : "v"(a), "v"(b))

// ---------- 6x6 packed-lower Cholesky ----------
__device__ __forceinline__ void chol6(const float* P, float* L, float* rd, float* sumlog) {
    float sl = 0.f;
    #pragma unroll
    for (int j = 0; j < 6; ++j) {
        float s = P[IDX(j,j)];
        #pragma unroll
        for (int m = 0; m < j; ++m) s -= L[IDX(j,m)] * L[IDX(j,m)];
        float d = sqrtf(s);
        L[IDX(j,j)] = d;
        float r = 1.0f / d;
        rd[j] = r;
        sl += logf(d);
        #pragma unroll
        for (int i = j + 1; i < 6; ++i) {
            float t = P[IDX(i,j)];
            #pragma unroll
            for (int m = 0; m < j; ++m) t -= L[IDX(i,m)] * L[IDX(j,m)];
            L[IDX(i,j)] = t * r;
        }
    }
    *sumlog = sl;
}

// ---------- K0: transpose X [B][D] -> Xt4 [D/4][B] (float4 per cell) ----------
__global__ __launch_bounds__(1024) void k_transpose4(const float* __restrict__ X,
                                                     float4* __restrict__ Xt4) {
    __shared__ float4 tile[32][33];
    int tx = threadIdx.x, ty = threadIdx.y;
    int d4b = blockIdx.x * 32;
    int bb  = blockIdx.y * 32;
    int d4 = d4b + tx;
    if (d4 < D_FT / 4)
        tile[ty][tx] = *(const float4*)&X[(size_t)(bb + ty) * D_FT + d4 * 4];
    __syncthreads();
    int d4o = d4b + ty;
    if (d4o < D_FT / 4)
        Xt4[(size_t)d4o * B_N + (bb + tx)] = tile[tx][ty];
}

// ---------- K0b: pack J bits -> JbT[w][b], w in [0,25) ----------
__global__ void k_packbits(const int* __restrict__ J, unsigned* __restrict__ JbT) {
    int t = blockIdx.x * blockDim.x + threadIdx.x;   // 2048*32 threads
    int b = t >> 5;
    int w = t & 31;
    if (w >= 25) return;
    int d0 = w * 32;
    int n = D_FT - d0; if (n > 32) n = 32;
    unsigned u = 0;
    for (int j = 0; j < n; ++j)
        u |= (J[(size_t)b * D_FT + d0 + j] != 0 ? 1u : 0u) << j;
    JbT[(size_t)w * B_N + b] = u;
}

// ---------- K0c: SJL[k][b] = sum_d Jf[b,d]*logD[k,d]  (into scores buffer) ----------
__global__ __launch_bounds__(256) void k_jld(const float* __restrict__ logD,
                                             const unsigned* __restrict__ JbT,
                                             float* __restrict__ SJL) {
    __shared__ float ld[800];
    const int k  = blockIdx.x >> 3;
    const int bt = blockIdx.x & 7;
    for (int i = threadIdx.x; i < 800; i += 256)
        ld[i] = (i < D_FT) ? logD[(size_t)k * D_FT + i] : 0.f;
    __syncthreads();
    const int b = bt * 256 + threadIdx.x;
    float jl = 0.f;
    for (int w = 0; w < 25; ++w) {
        unsigned mw = JbT[(size_t)w * B_N + b];
        const float* lw = &ld[w * 32];
        #pragma unroll
        for (int dd = 0; dd < 32; ++dd)
            jl += ((mw >> dd) & 1u) ? lw[dd] : 0.f;
    }
    SJL[(size_t)k * B_N + b] = jl;
}

// ---------- K1: per-(sample,k) accumulation + loglik, packed-f32 d-pairs ----------
// 256 threads = 64 samples x 4 d-quarters; quarter h covers words h*6..h*6+5
// (h==3: also the 16-bit tail word 24).
// Pair record (16 floats = 4x float4), d0=2p, d1=2p+1:
//   f4[0]={a~0(d0),a~0(d1),a~1(d0),a~1(d1)} f4[1]={a~2...a~3} f4[2]={a~4...a~5}
//   f4[3]={sa(d0),sa(d1),-mu(d0),-mu(d1)}   with a~ = sa*a, sa = exp(-logD/2)
// Math: m in {0,1};  z = m*sa*(x-mu);  P_ij += (m*a~_i)*a~_j;  q_j += z*a~_j;
//       quad += z*z.   (identical f32 algebra to the scalar version)
// NOTE: launch_bounds MUST stay (256,4): min-waves>=6 makes the allocator
// pick a spill schedule (r3: 32 VGPR/1.5GB scratch; r4: 40 VGPR/635MB).
#define ACC_PAIR(pi, dd, x0, x1) do { \
    const float4 f0 = sm4[(size_t)(pi) * 4 + 0]; \
    const float4 f1 = sm4[(size_t)(pi) * 4 + 1]; \
    const float4 f2 = sm4[(size_t)(pi) * 4 + 2]; \
    const float4 f3 = sm4[(size_t)(pi) * 4 + 3]; \
    v2f m2;  m2.x = (float)((mw >> (dd)) & 1u); m2.y = (float)((mw >> ((dd)+1)) & 1u); \
    v2f x2;  x2.x = (x0); x2.y = (x1); \
    v2f sa2;  sa2.x = f3.x;  sa2.y = f3.y; \
    v2f nmu2; nmu2.x = f3.z; nmu2.y = f3.w; \
    v2f a0; a0.x = f0.x; a0.y = f0.y;  v2f a1; a1.x = f0.z; a1.y = f0.w; \
    v2f a2; a2.x = f1.x; a2.y = f1.y;  v2f a3; a3.x = f1.z; a3.y = f1.w; \
    v2f a4; a4.x = f2.x; a4.y = f2.y;  v2f a5; a5.x = f2.z; a5.y = f2.w; \
    v2f w2;  PK_MUL(w2, m2, sa2); \
    v2f xm2; PK_ADD(xm2, x2, nmu2); \
    v2f z2;  PK_MUL(z2, w2, xm2); \
    v2f u; \
    PK_MUL(u, m2, a0); PK_FMA(Pm2[0],  u, a0); \
    PK_MUL(u, m2, a1); PK_FMA(Pm2[1],  u, a0); PK_FMA(Pm2[2],  u, a1); \
    PK_MUL(u, m2, a2); PK_FMA(Pm2[3],  u, a0); PK_FMA(Pm2[4],  u, a1); PK_FMA(Pm2[5],  u, a2); \
    PK_MUL(u, m2, a3); PK_FMA(Pm2[6],  u, a0); PK_FMA(Pm2[7],  u, a1); PK_FMA(Pm2[8],  u, a2); PK_FMA(Pm2[9],  u, a3); \
    PK_MUL(u, m2, a4); PK_FMA(Pm2[10], u, a0); PK_FMA(Pm2[11], u, a1); PK_FMA(Pm2[12], u, a2); PK_FMA(Pm2[13], u, a3); PK_FMA(Pm2[14], u, a4); \
    PK_MUL(u, m2, a5); PK_FMA(Pm2[15], u, a0); PK_FMA(Pm2[16], u, a1); PK_FMA(Pm2[17], u, a2); PK_FMA(Pm2[18], u, a3); PK_FMA(Pm2[19], u, a4); PK_FMA(Pm2[20], u, a5); \
    PK_FMA(qv2[0], z2, a0); PK_FMA(qv2[1], z2, a1); PK_FMA(qv2[2], z2, a2); \
    PK_FMA(qv2[3], z2, a3); PK_FMA(qv2[4], z2, a4); PK_FMA(qv2[5], z2, a5); \
    PK_FMA(quad2, z2, z2); \
} while (0)

__global__ __launch_bounds__(256, 4) void k_accum(
        const float4* __restrict__ Xt4, const unsigned* __restrict__ JbT,
        const float* __restrict__ A, const float* __restrict__ MU,
        const float* __restrict__ logD, const float* __restrict__ PI,
        float* __restrict__ scores, float* __restrict__ Pq) {
    __shared__ float4 sm4[(D_FT / 2) * 4];   // 392 pair-records x 64B = 25088 B
    float* smem = (float*)sm4;
    const int k   = blockIdx.x >> 5;
    const int tid = threadIdx.x;
    const int s   = tid & 63;
    const int h   = tid >> 6;           // d-quarter 0..3
    const int b   = (blockIdx.x & 31) * 64 + s;

    // stage pair-records (float4 writes -> conflict-light ds_write_b128)
    for (int p = tid; p < D_FT / 2; p += 256) {
        const float* ar0 = A + ((size_t)k * D_FT + 2 * p) * 6;
        const float* ar1 = ar0 + 6;
        float sa0 = expf(-0.5f * logD[(size_t)k * D_FT + 2 * p]);
        float sa1 = expf(-0.5f * logD[(size_t)k * D_FT + 2 * p + 1]);
        float4 f0, f1, f2, f3;
        f0.x = sa0 * ar0[0]; f0.y = sa1 * ar1[0]; f0.z = sa0 * ar0[1]; f0.w = sa1 * ar1[1];
        f1.x = sa0 * ar0[2]; f1.y = sa1 * ar1[2]; f1.z = sa0 * ar0[3]; f1.w = sa1 * ar1[3];
        f2.x = sa0 * ar0[4]; f2.y = sa1 * ar1[4]; f2.z = sa0 * ar0[5]; f2.w = sa1 * ar1[5];
        f3.x = sa0; f3.y = sa1;
        f3.z = -MU[(size_t)k * D_FT + 2 * p];
        f3.w = -MU[(size_t)k * D_FT + 2 * p + 1];
        sm4[(size_t)p * 4 + 0] = f0;
        sm4[(size_t)p * 4 + 1] = f1;
        sm4[(size_t)p * 4 + 2] = f2;
        sm4[(size_t)p * 4 + 3] = f3;
    }
    __syncthreads();

    v2f Pm2[21], qv2[6], quad2;
    #pragma unroll
    for (int t = 0; t < 21; ++t) { Pm2[t].x = 0.f; Pm2[t].y = 0.f; }
    #pragma unroll
    for (int t = 0; t < 6; ++t) { qv2[t].x = 0.f; qv2[t].y = 0.f; }
    quad2.x = 0.f; quad2.y = 0.f;
    int nob = 0;

    const int w0 = h * 6;
    const int w1 = w0 + 6;              // h==3: words 18..23 full, word 24 tail below
    for (int w = w0; w < w1; ++w) {
        const unsigned mw = JbT[(size_t)w * B_N + b];
        nob += __popc(mw);
        const int wpair = w * 16;
        const float4* xp = Xt4 + (size_t)(w * 8) * B_N + b;
        #pragma unroll 2
        for (int g = 0; g < 8; ++g) {
            float4 xv = xp[(size_t)g * B_N];
            ACC_PAIR(wpair + 2 * g,     g * 4,     xv.x, xv.y);
            ACC_PAIR(wpair + 2 * g + 1, g * 4 + 2, xv.z, xv.w);
        }
    }
    if (h == 3) {  // tail word 24: bits 0..15 valid (packed zeros above)
        const unsigned mw = JbT[(size_t)24 * B_N + b];
        nob += __popc(mw);
        const int wpair = 24 * 16;
        const float4* xp = Xt4 + (size_t)(24 * 8) * B_N + b;
        #pragma unroll
        for (int g = 0; g < 4; ++g) {
            float4 xv = xp[(size_t)g * B_N];
            ACC_PAIR(wpair + 2 * g,     g * 4,     xv.x, xv.y);
            ACC_PAIR(wpair + 2 * g + 1, g * 4 + 2, xv.z, xv.w);
        }
    }

    // horizontal add of packed halves
    float Pm[21], qv[6], quad;
    #pragma unroll
    for (int t = 0; t < 21; ++t) Pm[t] = Pm2[t].x + Pm2[t].y;
    #pragma unroll
    for (int t = 0; t < 6; ++t) qv[t] = qv2[t].x + qv2[t].y;
    quad = quad2.x + quad2.y;

    // merge the 4 d-quarters through LDS (staging buffer is dead now).
    // slabs: 64 samples x 33 floats, conflict-free (33 % 32 == 1).
    __syncthreads();
    float* red = smem;
    if (h & 1) {
        float* o = &red[(size_t)(h >> 1) * (64 * 33) + s * 33];
        #pragma unroll
        for (int t = 0; t < 21; ++t) o[t] = Pm[t];
        #pragma unroll
        for (int t = 0; t < 6; ++t) o[21 + t] = qv[t];
        o[27] = quad; o[28] = (float)nob;
    }
    __syncthreads();
    if (!(h & 1)) {
        const float* o = &red[(size_t)(h >> 1) * (64 * 33) + s * 33];
        #pragma unroll
        for (int t = 0; t < 21; ++t) Pm[t] += o[t];
        #pragma unroll
        for (int t = 0; t < 6; ++t) qv[t] += o[21 + t];
        quad += o[27]; nob += (int)o[28];
    }
    __syncthreads();
    if (h == 2) {
        float* o = &red[s * 33];
        #pragma unroll
        for (int t = 0; t < 21; ++t) o[t] = Pm[t];
        #pragma unroll
        for (int t = 0; t < 6; ++t) o[21 + t] = qv[t];
        o[27] = quad; o[28] = (float)nob;
    }
    __syncthreads();
    if (h == 0) {
        const float* o = &red[s * 33];
        #pragma unroll
        for (int t = 0; t < 21; ++t) Pm[t] += o[t];
        #pragma unroll
        for (int t = 0; t < 6; ++t) qv[t] += o[21 + t];
        quad += o[27];
        float nobs = (float)(nob + (int)o[28]);

        // jld precomputed by k_jld into the scores buffer (read before overwrite)
        float jld = scores[(size_t)k * B_N + b];

        // P = I + sum
        Pm[0] += 1.f; Pm[2] += 1.f; Pm[5] += 1.f; Pm[9] += 1.f; Pm[14] += 1.f; Pm[20] += 1.f;

        float Lm[21], rd[6], sumlog;
        chol6(Pm, Lm, rd, &sumlog);
        float y[6];
        #pragma unroll
        for (int j = 0; j < 6; ++j) {
            float sv = qv[j];
            #pragma unroll
            for (int m = 0; m < j; ++m) sv -= Lm[IDX(j,m)] * y[m];
            y[j] = sv * rd[j];
        }
        float yy = 0.f;
        #pragma unroll
        for (int j = 0; j < 6; ++j) yy += y[j] * y[j];
        float logdet = 2.f * sumlog + jld;
        float ll = -0.5f * ((quad - yy) + logdet + nobs * LOG2PI_F);
        float score = ll + PI[k];

        scores[(size_t)k * B_N + b] = score;
        float* pq = Pq + (size_t)k * 27 * B_N + b;
        #pragma unroll
        for (int t = 0; t < 21; ++t) pq[(size_t)t * B_N] = Pm[t];
        #pragma unroll
        for (int t = 0; t < 6; ++t) pq[(size_t)(21 + t) * B_N] = qv[t];
    }
}

// ---------- KC: argmax + latent solve per sample ----------
__global__ void k_select(const float* __restrict__ scores, const float* __restrict__ Pq,
                         int* __restrict__ csel, float* __restrict__ mzLz,
                         float* __restrict__ out) {
    int b = blockIdx.x * blockDim.x + threadIdx.x;
    if (b >= B_N) return;

    float best = scores[b];
    int bc = 0;
    for (int k = 1; k < K_N; ++k) {
        float s = scores[(size_t)k * B_N + b];
        if (s > best) { best = s; bc = k; }
    }
    csel[b] = bc;
    out[OUT_PW + b] = 1.0f;

    float Pm[21], qv[6];
    const float* pq = Pq + (size_t)bc * 27 * B_N + b;
    #pragma unroll
    for (int t = 0; t < 21; ++t) Pm[t] = pq[(size_t)t * B_N];
    #pragma unroll
    for (int t = 0; t < 6; ++t) qv[t] = pq[(size_t)(21 + t) * B_N];

    float Lm[21], rd[6], dummy;
    chol6(Pm, Lm, rd, &dummy);

    // forward: L y = q
    float y[6];
    #pragma unroll
    for (int j = 0; j < 6; ++j) {
        float s = qv[j];
        #pragma unroll
        for (int m = 0; m < j; ++m) s -= Lm[IDX(j,m)] * y[m];
        y[j] = s * rd[j];
    }
    // backward: L^T mz = y
    float mz[6];
    #pragma unroll
    for (int ii = 5; ii >= 0; --ii) {
        float s = y[ii];
        #pragma unroll
        for (int j = ii + 1; j < 6; ++j) s -= Lm[IDX(j,ii)] * mz[j];
        mz[ii] = s * rd[ii];
    }
    // Linv (packed lower)
    float Li[21];
    #pragma unroll
    for (int j = 0; j < 6; ++j) {
        Li[IDX(j,j)] = rd[j];
        #pragma unroll
        for (int i = j + 1; i < 6; ++i) {
            float s = 0.f;
            #pragma unroll
            for (int m = j; m < i; ++m) s += Lm[IDX(i,m)] * Li[IDX(m,j)];
            Li[IDX(i,j)] = -s * rd[i];
        }
    }
    // cov = Linv^T Linv (packed lower)
    float cov[21];
    #pragma unroll
    for (int i = 0; i < 6; ++i) {
        #pragma unroll
        for (int j = 0; j <= i; ++j) {
            float s = 0.f;
            #pragma unroll
            for (int m = i; m < 6; ++m) s += Li[IDX(m,i)] * Li[IDX(m,j)];
            cov[IDX(i,j)] = s;
        }
    }
    float Lz[21], rd2[6];
    chol6(cov, Lz, rd2, &dummy);

    float* o = mzLz + (size_t)b * 28;
    #pragma unroll
    for (int t = 0; t < 6; ++t) o[t] = mz[t];
    #pragma unroll
    for (int t = 0; t < 21; ++t) o[6 + t] = Lz[t];
}

// ---------- KD: write M, A_out, D_out ----------
__global__ __launch_bounds__(256) void k_output(
        const float* __restrict__ A, const float* __restrict__ MU,
        const float* __restrict__ logD, const int* __restrict__ csel,
        const float* __restrict__ mzLz, float* __restrict__ out) {
    __shared__ float smz[6];
    __shared__ float sLz[21];
    __shared__ int sc;
    int b = blockIdx.x;
    if (threadIdx.x == 0) sc = csel[b];
    if (threadIdx.x < 27) {
        float v = mzLz[(size_t)b * 28 + threadIdx.x];
        if (threadIdx.x < 6) smz[threadIdx.x] = v;
        else sLz[threadIdx.x - 6] = v;
    }
    __syncthreads();
    int c = sc;

    for (int d = threadIdx.x; d < D_FT; d += 256) {
        const float* ar = A + ((size_t)c * D_FT + d) * 6;
        float a[6];
        #pragma unroll
        for (int i = 0; i < 6; ++i) a[i] = ar[i];
        float mu = MU[(size_t)c * D_FT + d];
        float ld = logD[(size_t)c * D_FT + d];
        float m = mu;
        #pragma unroll
        for (int i = 0; i < 6; ++i) m += a[i] * smz[i];
        out[OUT_M + (size_t)b * D_FT + d] = m;
        out[OUT_D + (size_t)b * D_FT + d] = expf(ld);
        float* ao = out + OUT_A + ((size_t)b * D_FT + d) * 6;
        #pragma unroll
        for (int j = 0; j < 6; ++j) {
            float s = 0.f;
            #pragma unroll
            for (int i = j; i < 6; ++i) s += a[i] * sLz[IDX(i,j)];
            ao[j] = s;
        }
    }
}

extern "C" void kernel_launch(void* const* d_in, const int* in_sizes, int n_in,
                              void* d_out, int out_size, void* d_ws, size_t ws_size,
                              hipStream_t stream) {
    (void)in_sizes; (void)n_in; (void)out_size; (void)ws_size;
    const float* X    = (const float*)d_in[0];
    const int*   J    = (const int*)d_in[1];
    const float* MU   = (const float*)d_in[2];
    const float* A    = (const float*)d_in[3];
    const float* logD = (const float*)d_in[4];
    const float* PI   = (const float*)d_in[5];
    float* out = (float*)d_out;
    float* ws  = (float*)d_ws;

    float*    scores = ws + WS_SCORES;   // pre-accum: SJL (jld terms)
    float*    Pq     = ws + WS_PQ;
    int*      csel   = (int*)(ws + WS_C);
    float*    mzLz   = ws + WS_MZLZ;
    float4*   Xt4    = (float4*)(ws + WS_XT);
    unsigned* JbT    = (unsigned*)(ws + WS_JBT);

    dim3 g0((D_FT / 4 + 31) / 32, B_N / 32), b0(32, 32);
    k_transpose4<<<g0, b0, 0, stream>>>(X, Xt4);

    k_packbits<<<(B_N * 32) / 256, 256, 0, stream>>>(J, JbT);

    k_jld<<<K_N * 8, 256, 0, stream>>>(logD, JbT, scores);

    k_accum<<<32 * K_N, 256, 0, stream>>>(Xt4, JbT, A, MU, logD, PI, scores, Pq);

    k_select<<<B_N / 256, 256, 0, stream>>>(scores, Pq, csel, mzLz, out);

    k_output<<<B_N, 256, 0, stream>>>(A, MU, logD, csel, mzLz, out);
}